// Round 1
// 759.948 us; speedup vs baseline: 1.0089x; 1.0089x over previous
//
#include <hip/hip_runtime.h>
#include <cstdint>
#include <cstddef>

#define SEQ      4096
#define DIMIN    2048
#define HID      4096
#define STATE    128
#define HEADS    64
#define HEAD_DIM 64
#define CONV_DIM 4352   // HID + 2*STATE
#define D_IN     8512
#define WROWS    8576   // in_proj rows padded to 67*128
#define XBCD_N   4480   // xBC+dt GEMM cols: 4416 padded (row stride)
#define CHUNK    256
#define NCHUNK   16

typedef __attribute__((ext_vector_type(8))) short short8;
typedef __attribute__((ext_vector_type(4))) float floatx4;

#define AS1 __attribute__((address_space(1)))
#define AS3 __attribute__((address_space(3)))
__device__ __forceinline__ void gload_lds16(const void* g, void* l) {
    __builtin_amdgcn_global_load_lds((const AS1 unsigned int*)g, (AS3 unsigned int*)l, 16, 0, 0);
}

__device__ __forceinline__ unsigned short f2bf(float f) {
    union { float f; unsigned int u; } v; v.f = f;
    unsigned int r = v.u + 0x7FFFu + ((v.u >> 16) & 1u);
    return (unsigned short)(r >> 16);
}
__device__ __forceinline__ float bf2f(unsigned short u) {
    union { unsigned int u; float f; } v; v.u = ((unsigned int)u) << 16;
    return v.f;
}

// ---------------- fp32 -> bf16 convert (with zero tail padding) ----------------
__global__ void k_convert(const float* __restrict__ src, unsigned short* __restrict__ dst,
                          long n, long nsrc) {
    long i = (long)blockIdx.x * blockDim.x + threadIdx.x;
    if (i >= n) return;
    float v = (i < nsrc) ? src[i] : 0.f;
    dst[i] = f2bf(v);
}

// =====================================================================
// 256x256 deep-pipelined bf16 MFMA GEMM: C[M,N] = A[M,K] * B[N,K]^T
// 8 waves (512 thr), BK=64, 128 KiB double-buffered LDS.
// T2: zero-conflict slot^(row&7) swizzle (linear gload_lds dest, pre-swizzled
//     global source) — proven 0 SQ_LDS_BANK_CONFLICT in the 128^2 version.
// T3/T4: 4 phases/K-tile; staging for tile T spans (T-2).ph2..(T-1).ph1, so
//     the only in-loop wait is a counted vmcnt(4) (tile T+2's 2 pairs stay
//     in flight across the barrier — never drain-to-0).
// T5: setprio(1) around each 16-MFMA cluster.
// Pipeline safety (barrier-ordered, verified per-pair):
//   pair p covers rows p*64..p*64+63 of A and B in a buffer.
//   reads: A rows {0-63,128-191} in ph0, {64-127,192-255} in ph2;
//          B rows r with r%64<32 in ph0, r%64>=32 in ph1.
//   stage of (t+2,pair0) at t.ph2 is after end-of-ph1 barrier  -> safe.
//   stage of (t+2,pair1) at t.ph3 is after end-of-ph2 barrier  -> safe.
// Split-K: gridDim.z=2 halves K; bz=1 writes f32 partials to Cpart,
//   reduced afterwards by k_add (used for the 2048-col out-proj GEMM).
// =====================================================================
#define GBM 256
#define GBN 256
#define GBK 64

template <int BF16OUT>
__global__ __launch_bounds__(512, 2) void k_gemm256(
    const unsigned short* __restrict__ A, const unsigned short* __restrict__ B,
    void* __restrict__ Cout, float* __restrict__ Cpart,
    int Kloop, int ldk, int Nvalid, int ldc,
    float* __restrict__ aux, int auxc0)
{
    __shared__ __attribute__((aligned(16))) unsigned short As[2][GBM * GBK];
    __shared__ __attribute__((aligned(16))) unsigned short Bs[2][GBN * GBK];

    const int tid  = threadIdx.x;
    const int wid  = tid >> 6, lane = tid & 63;
    const int wm   = (wid >> 2) * 128;   // wave M offset in tile (2 M-halves)
    const int wn   = (wid & 3) * 64;     // wave N offset in tile (4 N-quarters)

    // bijective XCD-aware block swizzle (m204 form; works for any nwg)
    const int nbx = gridDim.x, nby = gridDim.y;
    const int nwg = nbx * nby * (int)gridDim.z;
    int flat = ((int)blockIdx.z * nby + blockIdx.y) * nbx + blockIdx.x;
    int q = nwg >> 3, r = nwg & 7;
    int xcd = flat & 7, loc = flat >> 3;
    int f2 = (xcd < r ? xcd * (q + 1) : r * (q + 1) + (xcd - r) * q) + loc;
    int bz  = f2 / (nbx * nby);
    int rm2 = f2 - bz * nbx * nby;
    int bm  = rm2 / nbx;
    int bn  = rm2 % nbx;

    const unsigned short* Ag = A + (long)bm * GBM * ldk + (long)bz * Kloop;
    const unsigned short* Bg = B + (long)bn * GBN * ldk + (long)bz * Kloop;

    // staging lane map: 8 lanes/row, slot s holds global k-group s^(row&7)
    const int s_r  = lane >> 3;
    const int s_kg = (lane & 7) ^ s_r;   // lane-constant since row%8 == s_r

    const int lrow = lane & 15;
    const int gk   = lane >> 4;

    floatx4 acc[8][4];
#pragma unroll
    for (int i = 0; i < 8; ++i)
#pragma unroll
        for (int j = 0; j < 4; ++j) acc[i][j] = (floatx4){0.f, 0.f, 0.f, 0.f};

    short8 aLo[4][2], aHi[4][2], bF[4][2];

    unsigned short* As0 = As[0]; unsigned short* Bs0 = Bs[0];
    unsigned short* As1 = As[1]; unsigned short* Bs1 = Bs[1];

    auto STAGE = [&](unsigned short* Ad, unsigned short* Bd, int tt, int p) {
        long k0 = (long)tt * GBK;
        if (k0 + GBK > Kloop) k0 = 0;    // dummy prefetch past K keeps vmcnt exact
        const int seg = p * 8 + wid;     // 8-row segment; wave writes seg*1024B linearly
        const long ro = (long)(seg * 8 + s_r) * ldk + k0 + s_kg * 8;
        gload_lds16(Ag + ro, Ad + seg * 512);
        gload_lds16(Bg + ro, Bd + seg * 512);
    };
    auto LDA_ = [&](unsigned short* Asu, int m, int ks) -> short8 {
        int row  = wm + m * 16 + lrow;
        int slot = (gk + ks * 4) ^ (lrow & 7);
        return *(const short8*)&Asu[row * 64 + slot * 8];
    };
    auto LDB_ = [&](unsigned short* Bsu, int n, int ks) -> short8 {
        int row  = wn + n * 16 + lrow;
        int slot = (gk + ks * 4) ^ (lrow & 7);
        return *(const short8*)&Bsu[row * 64 + slot * 8];
    };

    // prologue: tile0 pairs 0-3 + tile1 pairs 0-1; drain tile0, keep 4 in flight
#pragma unroll
    for (int p = 0; p < 4; ++p) STAGE(As0, Bs0, 0, p);
    STAGE(As1, Bs1, 1, 0);
    STAGE(As1, Bs1, 1, 1);
    asm volatile("s_waitcnt vmcnt(4)" ::: "memory");
    __builtin_amdgcn_s_barrier();
    asm volatile("" ::: "memory");

    const int nk = Kloop / GBK;          // even for all call sites

    auto tile_step = [&](unsigned short* Asu, unsigned short* Bsu,
                         unsigned short* AsN, unsigned short* BsN, int t) {
        // ---- phase 0: Q(m0-3, n0-1); stage (t+1, pair2) -> other buf ----
#pragma unroll
        for (int m = 0; m < 4; ++m) { aLo[m][0] = LDA_(Asu, m, 0); aLo[m][1] = LDA_(Asu, m, 1); }
#pragma unroll
        for (int n = 0; n < 2; ++n) { bF[n][0] = LDB_(Bsu, n, 0); bF[n][1] = LDB_(Bsu, n, 1); }
        STAGE(AsN, BsN, t + 1, 2);
        __builtin_amdgcn_s_barrier();
        asm volatile("" ::: "memory");
        __builtin_amdgcn_s_setprio(1);
#pragma unroll
        for (int m = 0; m < 4; ++m)
#pragma unroll
            for (int n = 0; n < 2; ++n)
#pragma unroll
                for (int ks = 0; ks < 2; ++ks)
                    acc[m][n] = __builtin_amdgcn_mfma_f32_16x16x32_bf16(aLo[m][ks], bF[n][ks], acc[m][n], 0, 0, 0);
        __builtin_amdgcn_s_setprio(0);
        __builtin_amdgcn_s_barrier();
        asm volatile("" ::: "memory");
        // ---- phase 1: Q(m0-3, n2-3); stage (t+1, pair3) ----
#pragma unroll
        for (int n = 2; n < 4; ++n) { bF[n][0] = LDB_(Bsu, n, 0); bF[n][1] = LDB_(Bsu, n, 1); }
        STAGE(AsN, BsN, t + 1, 3);
        __builtin_amdgcn_s_barrier();
        asm volatile("" ::: "memory");
        __builtin_amdgcn_s_setprio(1);
#pragma unroll
        for (int m = 0; m < 4; ++m)
#pragma unroll
            for (int n = 2; n < 4; ++n)
#pragma unroll
                for (int ks = 0; ks < 2; ++ks)
                    acc[m][n] = __builtin_amdgcn_mfma_f32_16x16x32_bf16(aLo[m][ks], bF[n][ks], acc[m][n], 0, 0, 0);
        __builtin_amdgcn_s_setprio(0);
        __builtin_amdgcn_s_barrier();
        asm volatile("" ::: "memory");
        // ---- phase 2: Q(m4-7, n2-3); stage (t+2, pair0) -> CURRENT buf ----
#pragma unroll
        for (int m = 0; m < 4; ++m) { aHi[m][0] = LDA_(Asu, m + 4, 0); aHi[m][1] = LDA_(Asu, m + 4, 1); }
        STAGE(Asu, Bsu, t + 2, 0);
        __builtin_amdgcn_s_barrier();
        asm volatile("" ::: "memory");
        __builtin_amdgcn_s_setprio(1);
#pragma unroll
        for (int m = 0; m < 4; ++m)
#pragma unroll
            for (int n = 2; n < 4; ++n)
#pragma unroll
                for (int ks = 0; ks < 2; ++ks)
                    acc[m + 4][n] = __builtin_amdgcn_mfma_f32_16x16x32_bf16(aHi[m][ks], bF[n][ks], acc[m + 4][n], 0, 0, 0);
        __builtin_amdgcn_s_setprio(0);
        __builtin_amdgcn_s_barrier();
        asm volatile("" ::: "memory");
        // ---- phase 3: Q(m4-7, n0-1); stage (t+2, pair1); counted drain ----
        STAGE(Asu, Bsu, t + 2, 1);
        __builtin_amdgcn_s_barrier();
        asm volatile("" ::: "memory");
        __builtin_amdgcn_s_setprio(1);
#pragma unroll
        for (int m = 0; m < 4; ++m)
#pragma unroll
            for (int n = 0; n < 2; ++n)
#pragma unroll
                for (int ks = 0; ks < 2; ++ks)
                    acc[m + 4][n] = __builtin_amdgcn_mfma_f32_16x16x32_bf16(aHi[m][ks], bF[n][ks], acc[m + 4][n], 0, 0, 0);
        __builtin_amdgcn_s_setprio(0);
        // drain tile t+1's 8 loads; keep tile t+2's pair0/pair1 (4) in flight
        asm volatile("s_waitcnt vmcnt(4)" ::: "memory");
        __builtin_amdgcn_s_barrier();
        asm volatile("" ::: "memory");
    };

#pragma unroll 1
    for (int t = 0; t < nk; t += 2) {
        tile_step(As0, Bs0, As1, Bs1, t);
        tile_step(As1, Bs1, As0, Bs0, t + 1);
    }

    // ---- epilogue: C/D layout col=lane&15, row=(lane>>4)*4+reg ----
    const int rcol = lane & 15, rrow = (lane >> 4) * 4;
#pragma unroll
    for (int m = 0; m < 8; ++m)
#pragma unroll
        for (int n = 0; n < 4; ++n) {
            const int colb = bn * GBN + wn + n * 16;
            if (colb >= Nvalid) continue;   // pad-tile fragments (garbage B) masked
            const int col = colb + rcol;
#pragma unroll
            for (int r2 = 0; r2 < 4; ++r2) {
                const int row = bm * GBM + wm + m * 16 + rrow + r2;
                float v = acc[m][n][r2];
                if (BF16OUT) {
                    ((unsigned short*)Cout)[(long)row * ldc + col] = f2bf(v);
                    if (aux && col >= auxc0 && col < auxc0 + 64)
                        aux[(long)row * 64 + (col - auxc0)] = v;
                } else {
                    float* op = bz ? Cpart : (float*)Cout;
                    op[(long)row * ldc + col] = v;
                }
            }
        }
}

// ---------------- split-K reduction: dst += src (f32, vectorized) ----------------
__global__ void k_add(float* __restrict__ dst, const float* __restrict__ src, long n4) {
    long i = (long)blockIdx.x * blockDim.x + threadIdx.x;
    if (i >= n4) return;
    float4 a = ((const float4*)src)[i];
    float4 d = ((float4*)dst)[i];
    d.x += a.x; d.y += a.y; d.z += a.z; d.w += a.w;
    ((float4*)dst)[i] = d;
}

// ---------------- causal conv1d (k=4) + SiLU, bf16 in/out ----------------
__global__ void k_conv(const unsigned short* __restrict__ xbcd, const float* __restrict__ convw,
                       unsigned short* __restrict__ xc) {
    long i = (long)blockIdx.x * 256 + threadIdx.x;
    if (i >= (long)SEQ * CONV_DIM) return;
    int c = (int)(i % CONV_DIM);
    int s = (int)(i / CONV_DIM);
    float w0 = convw[c * 4 + 0], w1 = convw[c * 4 + 1];
    float w2 = convw[c * 4 + 2], w3 = convw[c * 4 + 3];
    float acc = bf2f(xbcd[(long)s * XBCD_N + c]) * w3;
    if (s >= 1) acc += bf2f(xbcd[(long)(s - 1) * XBCD_N + c]) * w2;
    if (s >= 2) acc += bf2f(xbcd[(long)(s - 2) * XBCD_N + c]) * w1;
    if (s >= 3) acc += bf2f(xbcd[(long)(s - 3) * XBCD_N + c]) * w0;
    float sl = acc / (1.f + __expf(-acc));
    xc[i] = f2bf(sl);
}

// ---------------- dt = softplus(dtraw+bias), dA = dt*A, per-chunk inclusive cumsum ----------------
__global__ __launch_bounds__(256) void k_dt(const float* __restrict__ dtraw,
        const float* __restrict__ dt_bias, const float* __restrict__ A_log,
        float* __restrict__ dtv, float* __restrict__ dAc, float* __restrict__ dAlast)
{
    int c = blockIdx.x, h = blockIdx.y;
    int l = threadIdx.x;
    __shared__ float sh[CHUNK];
    float v = dtraw[(long)(c * CHUNK + l) * 64 + h] + dt_bias[h];
    float dt = (v > 20.f) ? v : log1pf(__expf(v));
    float Ah = -__expf(A_log[h]);
    float dA = dt * Ah;
    sh[l] = dA;
    __syncthreads();
    float x = dA;
#pragma unroll
    for (int off = 1; off < CHUNK; off <<= 1) {
        float t = (l >= off) ? sh[l - off] : 0.f;
        __syncthreads();
        x += t;
        sh[l] = x;
        __syncthreads();
    }
    dtv[(long)(c * CHUNK + l) * HEADS + h] = dt;
    dAc[(long)(c * CHUNK + l) * HEADS + h] = x;
    if (l == CHUNK - 1) dAlast[c * HEADS + h] = x;
}

// ---------------- G[c][l][s] = C[l] . B[s] ----------------
__global__ __launch_bounds__(256) void k_G(const unsigned short* __restrict__ xc, float* __restrict__ G) {
    int c = blockIdx.x, l = blockIdx.y;
    int s = threadIdx.x;
    __shared__ float Csh[STATE];
    if (s < STATE) Csh[s] = bf2f(xc[(long)(c * CHUNK + l) * CONV_DIM + HID + STATE + s]);
    __syncthreads();
    const unsigned short* Brow = xc + (long)(c * CHUNK + s) * CONV_DIM + HID;
    float acc = 0.f;
#pragma unroll
    for (int n = 0; n < STATE; n += 8) {
        short8 b8 = *(const short8*)&Brow[n];
#pragma unroll
        for (int j = 0; j < 8; ++j)
            acc += Csh[n + j] * bf2f((unsigned short)b8[j]);
    }
    G[((long)c * CHUNK + l) * CHUNK + s] = acc;
}

// ---------------- states[c,h,p,n] = sum_l B[l,n]*exp(dAlast-dAc[l])*dt[l]*xh[l,p] ----------------
__global__ __launch_bounds__(256) void k_states(
    const unsigned short* __restrict__ xc, const float* __restrict__ dtv,
    const float* __restrict__ dAc, const float* __restrict__ dAlast,
    float* __restrict__ states)
{
    int c = blockIdx.x, h = blockIdx.y;
    int t = threadIdx.x;
    __shared__ float xs[64][64];
    __shared__ float dA_sh[CHUNK], dt_sh[CHUNK];
    long base_s = (long)c * CHUNK;
    dA_sh[t] = dAc[(base_s + t) * HEADS + h];
    dt_sh[t] = dtv[(base_s + t) * HEADS + h];
    __syncthreads();
    float dAl = dAlast[c * HEADS + h];
    int p0 = t >> 5;
    int n0 = t & 31;
    float acc[8][4];
#pragma unroll
    for (int ip = 0; ip < 8; ++ip)
#pragma unroll
        for (int j = 0; j < 4; ++j) acc[ip][j] = 0.f;

    for (int lb = 0; lb < 4; ++lb) {
#pragma unroll
        for (int i = 0; i < 16; ++i) {
            int e = t + i * 256;
            int r = e >> 6, pcol = e & 63;
            float ds = __expf(dAl - dA_sh[lb * 64 + r]) * dt_sh[lb * 64 + r];
            xs[r][pcol] = bf2f(xc[(base_s + lb * 64 + r) * CONV_DIM + h * HEAD_DIM + pcol]) * ds;
        }
        __syncthreads();
        for (int lp = 0; lp < 64; ++lp) {
            const unsigned short* Brow = xc + (base_s + lb * 64 + lp) * CONV_DIM + HID;
            float bv[4];
#pragma unroll
            for (int j = 0; j < 4; ++j) bv[j] = bf2f(Brow[n0 + 32 * j]);
#pragma unroll
            for (int ip = 0; ip < 8; ++ip) {
                float xv = xs[lp][p0 + 8 * ip];
#pragma unroll
                for (int j = 0; j < 4; ++j) acc[ip][j] += xv * bv[j];
            }
        }
        __syncthreads();
    }
    float* Sb = states + (long)(c * HEADS + h) * HEAD_DIM * STATE;
#pragma unroll
    for (int ip = 0; ip < 8; ++ip)
#pragma unroll
        for (int j = 0; j < 4; ++j)
            Sb[(p0 + 8 * ip) * STATE + n0 + 32 * j] = acc[ip][j];
}

// ---------------- sequential chunk-state scan (in place: states[c] := prev state) ----------------
__global__ void k_scan(float* __restrict__ states, const float* __restrict__ dAlast) {
    int t = blockIdx.x * 256 + threadIdx.x;
    if (t >= HEADS * HEAD_DIM * STATE) return;
    int h = t >> 13;
    const long stride = (long)HEADS * HEAD_DIM * STATE;
    float carry = 0.f;
    for (int c = 0; c < NCHUNK; ++c) {
        float s = states[c * stride + t];
        float dec = __expf(dAlast[c * HEADS + h]);
        states[c * stride + t] = carry;
        carry = carry * dec + s;
    }
}

// ---------------- y = y_off + y_diag + D*x (MFMA version), bf16 out ----------------
#define XDTS 264   // row stride: 528 B -> 16B-aligned rows, 4-bank advance (2-way, free)
#define PVS  136   // row stride: 272 B -> same property
__global__ __launch_bounds__(256, 3) void k_ssd_y(
    const unsigned short* __restrict__ xc, const float* __restrict__ G,
    const float* __restrict__ dtv, const float* __restrict__ dAc,
    const float* __restrict__ prev, const float* __restrict__ Dp,
    unsigned short* __restrict__ y)
{
    __shared__ __attribute__((aligned(16))) unsigned short xdtT[64 * XDTS];
    __shared__ __attribute__((aligned(16))) unsigned short pvB[64 * PVS];
    __shared__ float dA_sh[CHUNK];
    __shared__ float dt_sh[CHUNK];
    const int c = blockIdx.x, h = blockIdx.y;
    const int t = threadIdx.x;
    const int w = t >> 6, lane = t & 63;
    const long base_s = (long)c * CHUNK;

    dA_sh[t] = dAc[(base_s + t) * HEADS + h];
    dt_sh[t] = dtv[(base_s + t) * HEADS + h];
    __syncthreads();

    {
        const float* Pb = prev + (long)(c * HEADS + h) * HEAD_DIM * STATE;
#pragma unroll
        for (int i = 0; i < 32; ++i) {
            int e = t + i * 256;
            int p = e >> 7, n = e & 127;
            pvB[p * PVS + n] = f2bf(Pb[e]);
        }
    }
#pragma unroll
    for (int i = 0; i < 64; ++i) {
        int e = t + i * 256;
        int p = e & 63, s = e >> 6;
        float v = bf2f(xc[(base_s + s) * CONV_DIM + h * HEAD_DIM + p]) * dt_sh[s];
        xdtT[p * XDTS + s] = f2bf(v);
    }
    __syncthreads();

    floatx4 acc[4][4];
#pragma unroll
    for (int i = 0; i < 4; ++i)
#pragma unroll
        for (int j = 0; j < 4; ++j) acc[i][j] = (floatx4){0.f, 0.f, 0.f, 0.f};

    const int lrow = lane & 15;
    const int kgrp = (lane >> 4) * 8;
    float myA[4], eAl[4];
#pragma unroll
    for (int i = 0; i < 4; ++i) {
        int l = w * 64 + i * 16 + lrow;
        myA[i] = dA_sh[l];
        eAl[i] = __expf(myA[i]);
    }

    // ---- off term: k = n over STATE ----
    for (int k0 = 0; k0 < STATE; k0 += 32) {
        short8 af[4], bfr[4];
#pragma unroll
        for (int i = 0; i < 4; ++i) {
            int l = w * 64 + i * 16 + lrow;
            union { short8 v; unsigned short u[8]; } r, o;
            r.v = *(const short8*)&xc[(base_s + l) * CONV_DIM + (HID + STATE) + k0 + kgrp];
#pragma unroll
            for (int j = 0; j < 8; ++j) o.u[j] = f2bf(bf2f(r.u[j]) * eAl[i]);
            af[i] = o.v;
        }
#pragma unroll
        for (int j = 0; j < 4; ++j)
            bfr[j] = *(const short8*)&pvB[(j * 16 + lrow) * PVS + k0 + kgrp];
#pragma unroll
        for (int i = 0; i < 4; ++i)
#pragma unroll
            for (int j = 0; j < 4; ++j)
                acc[i][j] = __builtin_amdgcn_mfma_f32_16x16x32_bf16(af[i], bfr[j], acc[i][j], 0, 0, 0);
    }

    // ---- diag term: k = s, only tiles not fully above the diagonal ----
    for (int k0 = 0; k0 < (w + 1) * 64; k0 += 32) {
        short8 af[4], bfr[4];
#pragma unroll
        for (int i = 0; i < 4; ++i) {
            int l = w * 64 + i * 16 + lrow;
            const float* Gp = G + (base_s + l) * (long)CHUNK + k0 + kgrp;
            float4 g0 = *(const float4*)Gp;
            float4 g1 = *(const float4*)(Gp + 4);
            float ga[8] = {g0.x, g0.y, g0.z, g0.w, g1.x, g1.y, g1.z, g1.w};
            union { short8 v; unsigned short u[8]; } o;
#pragma unroll
            for (int j = 0; j < 8; ++j) {
                int s = k0 + kgrp + j;
                float e = __expf(fminf(myA[i] - dA_sh[s], 0.f));
                float m = (s <= l) ? ga[j] * e : 0.f;
                o.u[j] = f2bf(m);
            }
            af[i] = o.v;
        }
#pragma unroll
        for (int j = 0; j < 4; ++j)
            bfr[j] = *(const short8*)&xdtT[(j * 16 + lrow) * XDTS + k0 + kgrp];
#pragma unroll
        for (int i = 0; i < 4; ++i)
#pragma unroll
            for (int j = 0; j < 4; ++j)
                acc[i][j] = __builtin_amdgcn_mfma_f32_16x16x32_bf16(af[i], bfr[j], acc[i][j], 0, 0, 0);
    }

    // ---- epilogue: + D*x, bf16 store ----
    const float Dh = Dp[h];
    const int rrow = (lane >> 4) * 4;
#pragma unroll
    for (int i = 0; i < 4; ++i)
#pragma unroll
        for (int j = 0; j < 4; ++j) {
            int p = j * 16 + lrow;
#pragma unroll
            for (int r = 0; r < 4; ++r) {
                int l = w * 64 + i * 16 + rrow + r;
                float v = acc[i][j][r] + Dh * bf2f(xc[(base_s + l) * CONV_DIM + h * HEAD_DIM + p]);
                y[(base_s + l) * (long)HID + h * HEAD_DIM + p] = f2bf(v);
            }
        }
}

// ---------------- gate with silu(z), RMSNorm, bf16 out ----------------
__global__ __launch_bounds__(256) void k_norm(
    const unsigned short* __restrict__ y, const unsigned short* __restrict__ z,
    const float* __restrict__ norm_w, unsigned short* __restrict__ yb)
{
    int s = blockIdx.x;
    int t = threadIdx.x;
    const unsigned short* yrow = y + (long)s * HID;
    const unsigned short* zrow = z + (long)s * HID;
    float vals[16];
    float ss = 0.f;
#pragma unroll
    for (int i = 0; i < 16; ++i) {
        int j = t + i * 256;
        float yv = bf2f(yrow[j]);
        float zv = bf2f(zrow[j]);
        float g = yv * (zv / (1.f + __expf(-zv)));
        vals[i] = g;
        ss += g * g;
    }
#pragma unroll
    for (int off = 32; off > 0; off >>= 1) ss += __shfl_down(ss, off);
    __shared__ float wsum[4];
    int lane = t & 63, wid = t >> 6;
    if (lane == 0) wsum[wid] = ss;
    __syncthreads();
    float total = wsum[0] + wsum[1] + wsum[2] + wsum[3];
    float scale = rsqrtf(total / HID + 1e-5f);
#pragma unroll
    for (int i = 0; i < 16; ++i) {
        int j = t + i * 256;
        yb[(long)s * HID + j] = f2bf(vals[i] * scale * norm_w[j]);
    }
}

// ---------------- launch ----------------
extern "C" void kernel_launch(void* const* d_in, const int* in_sizes, int n_in,
                              void* d_out, int out_size, void* d_ws, size_t ws_size,
                              hipStream_t stream) {
    const float* x          = (const float*)d_in[0];
    const float* in_proj_w  = (const float*)d_in[1];
    const float* conv_w     = (const float*)d_in[2];
    const float* dt_bias    = (const float*)d_in[3];
    const float* A_log      = (const float*)d_in[4];
    const float* Dp         = (const float*)d_in[5];
    const float* norm_w     = (const float*)d_in[6];
    const float* out_proj_w = (const float*)d_in[7];
    char* ws = (char*)d_ws;

    // workspace layout (bytes) — total 131,600,384 (unchanged)
    const size_t off_xb    = 0;
    const size_t off_wbin  = off_xb    + (size_t)SEQ * DIMIN * 2;
    const size_t off_xbcd  = off_wbin  + (size_t)WROWS * DIMIN * 2;
    const size_t off_xc    = off_xbcd  + (size_t)SEQ * XBCD_N * 2;
    const size_t off_dtraw = off_xc    + (size_t)SEQ * CONV_DIM * 2;
    const size_t off_dtv   = off_dtraw + (size_t)SEQ * 64 * 4;
    const size_t off_dAc   = off_dtv   + (size_t)SEQ * HEADS * 4;
    const size_t off_dAl   = off_dAc   + (size_t)SEQ * HEADS * 4;
    const size_t off_G     = off_dAl   + (size_t)NCHUNK * HEADS * 4;
    const size_t needed    = off_G     + (size_t)NCHUNK * CHUNK * CHUNK * 4;
    if (ws_size < needed) return;

    unsigned short* xb    = (unsigned short*)(ws + off_xb);
    unsigned short* wbin  = (unsigned short*)(ws + off_wbin);
    unsigned short* xbcd  = (unsigned short*)(ws + off_xbcd);
    unsigned short* xc    = (unsigned short*)(ws + off_xc);
    float* dtraw = (float*)(ws + off_dtraw);
    float* dtv   = (float*)(ws + off_dtv);
    float* dAc   = (float*)(ws + off_dAc);
    float* dAl   = (float*)(ws + off_dAl);
    float* G     = (float*)(ws + off_G);

    float* states      = (float*)d_out;
    unsigned short* z  = (unsigned short*)d_out;
    unsigned short* y  = xbcd;
    unsigned short* yb = xc;
    unsigned short* wob = wbin;
    float* gpart = (float*)(ws + off_xbcd);   // split-K partials; xbcd dead by GEMM3

    { long n = (long)SEQ * DIMIN;
      k_convert<<<(unsigned)((n + 255) / 256), 256, 0, stream>>>(x, xb, n, n); }
    { long n = (long)WROWS * DIMIN, nsrc = (long)D_IN * DIMIN;
      k_convert<<<(unsigned)((n + 255) / 256), 256, 0, stream>>>(in_proj_w, wbin, n, nsrc); }
    // GEMM1: xBC+dt. 18 N-tiles (4608 covered, stores masked to <4480);
    // B rows 4480-4607 over-read land in allocated ws and feed masked fragments only.
    k_gemm256<1><<<dim3((XBCD_N + GBN - 1) / GBN, SEQ / GBM, 1), 512, 0, stream>>>(
        xb, wbin + (size_t)HID * DIMIN, (void*)xbcd, nullptr,
        DIMIN, DIMIN, XBCD_N, XBCD_N, dtraw, 4352);
    { long n = (long)SEQ * CONV_DIM;
      k_conv<<<(unsigned)((n + 255) / 256), 256, 0, stream>>>(xbcd, conv_w, xc); }
    k_dt<<<dim3(NCHUNK, HEADS), 256, 0, stream>>>(dtraw, dt_bias, A_log, dtv, dAc, dAl);
    k_G<<<dim3(NCHUNK, CHUNK), 256, 0, stream>>>(xc, G);
    k_states<<<dim3(NCHUNK, HEADS), 256, 0, stream>>>(xc, dtv, dAc, dAl, states);
    k_scan<<<(HEADS * HEAD_DIM * STATE) / 256, 256, 0, stream>>>(states, dAl);
    k_ssd_y<<<dim3(NCHUNK, HEADS), 256, 0, stream>>>(xc, G, dtv, dAc, states, Dp, y);
    // GEMM2: z-gate (16x16 tiles = 256 blocks, exactly 1/CU)
    k_gemm256<1><<<dim3(HID / GBN, SEQ / GBM, 1), 512, 0, stream>>>(
        xb, wbin, (void*)z, nullptr, DIMIN, DIMIN, HID, HID, nullptr, 0);
    k_norm<<<SEQ, 256, 0, stream>>>(y, z, norm_w, yb);
    { long n = (long)DIMIN * HID;
      k_convert<<<(unsigned)((n + 255) / 256), 256, 0, stream>>>(out_proj_w, wob, n, n); }
    // GEMM3: out-proj, split-K=2 (8x16x2 = 256 blocks); z=1 partials -> gpart
    k_gemm256<0><<<dim3(DIMIN / GBN, SEQ / GBM, 2), 512, 0, stream>>>(
        yb, wob, d_out, gpart, HID / 2, HID, DIMIN, DIMIN, nullptr, 0);
    k_add<<<(unsigned)(((long)SEQ * DIMIN / 4 + 255) / 256), 256, 0, stream>>>(
        (float*)d_out, gpart, (long)SEQ * DIMIN / 4);
}

// Round 2
// 726.090 us; speedup vs baseline: 1.0559x; 1.0466x over previous
//
#include <hip/hip_runtime.h>
#include <cstdint>
#include <cstddef>

#define SEQ      4096
#define DIMIN    2048
#define HID      4096
#define STATE    128
#define HEADS    64
#define HEAD_DIM 64
#define CONV_DIM 4352   // HID + 2*STATE
#define D_IN     8512
#define WROWS    8576   // in_proj rows padded to 67*128
#define XBCD_N   4480   // xBC+dt GEMM cols: 4416 padded (row stride)
#define CHUNK    256
#define NCHUNK   16

typedef __attribute__((ext_vector_type(8))) short short8;
typedef __attribute__((ext_vector_type(4))) float floatx4;
typedef __attribute__((ext_vector_type(4))) int   intx4;

#define AS1 __attribute__((address_space(1)))
#define AS3 __attribute__((address_space(3)))
__device__ __forceinline__ void gload_lds16(const void* g, void* l) {
    __builtin_amdgcn_global_load_lds((const AS1 unsigned int*)g, (AS3 unsigned int*)l, 16, 0, 0);
}

__device__ __forceinline__ unsigned short f2bf(float f) {
    union { float f; unsigned int u; } v; v.f = f;
    unsigned int r = v.u + 0x7FFFu + ((v.u >> 16) & 1u);
    return (unsigned short)(r >> 16);
}
__device__ __forceinline__ float bf2f(unsigned short u) {
    union { unsigned int u; float f; } v; v.u = ((unsigned int)u) << 16;
    return v.f;
}
__device__ __forceinline__ short8 asv(intx4 x) {
    union { intx4 i; short8 s; } u; u.i = x; return u.s;
}

// inline-asm ds_read_b128: invisible to the compiler's LDS-DMA waitcnt
// tracking, so NO conservative vmcnt(0) is inserted before it. Ordering vs
// global_load_lds is carried by our explicit vmcnt(4)+barrier discipline.
#define DSR(dst, ptr, off) \
    asm volatile("ds_read_b128 %0, %1 offset:" off : "=&v"(dst) : "v"(ptr))
#define SB0   __builtin_amdgcn_sched_barrier(0)
#define BAR   __builtin_amdgcn_s_barrier()
#define LGKM0 asm volatile("s_waitcnt lgkmcnt(0)" ::: "memory")
#define VMC4  asm volatile("s_waitcnt vmcnt(4)" ::: "memory")

// ---------------- fp32 -> bf16 convert (with zero tail padding) ----------------
__global__ void k_convert(const float* __restrict__ src, unsigned short* __restrict__ dst,
                          long n, long nsrc) {
    long i = (long)blockIdx.x * blockDim.x + threadIdx.x;
    if (i >= n) return;
    float v = (i < nsrc) ? src[i] : 0.f;
    dst[i] = f2bf(v);
}

// =====================================================================
// 256x256 deep-pipelined bf16 MFMA GEMM: C[M,N] = A[M,K] * B[N,K]^T
// 8 waves (512 thr), BK=64, 128 KiB double-buffered LDS.
// Round-2 change vs round-1 (schedule IDENTICAL): all inner-loop LDS reads
// are inline-asm ds_read_b128 (precomputed AS3 base pointers + literal
// offsets). Round-1's plain-HIP reads triggered conservative compiler
// vmcnt waits against outstanding global_load_lds (LDS-DMA alias tracking
// is imprecise beyond a few ops), collapsing the prefetch pipeline
// (MfmaUtil 19%, all pipes idle). Explicit lgkmcnt(0)+sched_barrier(0)
// per phase (rule #18) replaces compiler-auto waits for the asm reads.
// Pipeline safety (unchanged, barrier-ordered, verified per-pair):
//   pair p covers rows p*64..p*64+63 of A and B in a buffer.
//   reads: A rows {0-63,128-191} in ph0, {64-127,192-255} in ph2;
//          B rows r with r%64<32 in ph0, r%64>=32 in ph1.
//   stage of (t+2,pair0) at t.ph2 is after end-of-ph1 barrier  -> safe.
//   stage of (t+2,pair1) at t.ph3 is after end-of-ph2 barrier  -> safe.
//   vmcnt(4) at t.ph3 drains (t+1)'s 8 loads, keeps (t+2) pair0/1 in flight.
// =====================================================================
#define GBM 256
#define GBN 256
#define GBK 64

template <int BF16OUT>
__global__ __launch_bounds__(512, 2) void k_gemm256(
    const unsigned short* __restrict__ A, const unsigned short* __restrict__ B,
    void* __restrict__ Cout, float* __restrict__ Cpart,
    int Kloop, int ldk, int Nvalid, int ldc,
    float* __restrict__ aux, int auxc0)
{
    // one array, 4 partitions (shorts): As0=0, Bs0=16384, As1=32768, Bs1=49152
    __shared__ __attribute__((aligned(16))) unsigned short smem[4 * 16384];

    const int tid  = threadIdx.x;
    const int wid  = tid >> 6, lane = tid & 63;
    const int wm   = (wid >> 2) * 128;   // wave M offset in tile (2 M-halves)
    const int wn   = (wid & 3) * 64;     // wave N offset in tile (4 N-quarters)

    // bijective XCD-aware block swizzle (m204 form; works for any nwg)
    const int nbx = gridDim.x, nby = gridDim.y;
    const int nwg = nbx * nby * (int)gridDim.z;
    int flat = ((int)blockIdx.z * nby + blockIdx.y) * nbx + blockIdx.x;
    int q = nwg >> 3, r = nwg & 7;
    int xcd = flat & 7, loc = flat >> 3;
    int f2 = (xcd < r ? xcd * (q + 1) : r * (q + 1) + (xcd - r) * q) + loc;
    int bz  = f2 / (nbx * nby);
    int rm2 = f2 - bz * nbx * nby;
    int bm  = rm2 / nbx;
    int bn  = rm2 % nbx;

    const unsigned short* Ag = A + (long)bm * GBM * ldk + (long)bz * Kloop;
    const unsigned short* Bg = B + (long)bn * GBN * ldk + (long)bz * Kloop;

    // staging lane map: 8 lanes/row, slot s holds global k-group s^(row&7)
    const int s_r  = lane >> 3;
    const int s_kg = (lane & 7) ^ s_r;   // lane-constant since row%8 == s_r

    const int lrow = lane & 15;
    const int gk   = lane >> 4;
    const int slot0 = gk ^ (lrow & 7);

    // read base indices (shorts). slot1 = slot0^4 -> index ^ 32 shorts.
    const int aIdx0 = (wm + lrow) * 64 + slot0 * 8;
    const int bIdx0 = (wn + lrow) * 64 + slot0 * 8;
    const AS3 unsigned short* sm3 = (const AS3 unsigned short*)smem;
    const AS3 unsigned short* pA0k0 = sm3 + aIdx0;
    const AS3 unsigned short* pA0k1 = sm3 + (aIdx0 ^ 32);
    const AS3 unsigned short* pA1k0 = sm3 + 32768 + aIdx0;
    const AS3 unsigned short* pA1k1 = sm3 + 32768 + (aIdx0 ^ 32);
    const AS3 unsigned short* pB0k0 = sm3 + 16384 + bIdx0;
    const AS3 unsigned short* pB0k1 = sm3 + 16384 + (bIdx0 ^ 32);
    const AS3 unsigned short* pB1k0 = sm3 + 49152 + bIdx0;
    const AS3 unsigned short* pB1k1 = sm3 + 49152 + (bIdx0 ^ 32);

    unsigned short* AdB0 = smem;            // generic ptrs for STAGE dests
    unsigned short* BdB0 = smem + 16384;
    unsigned short* AdB1 = smem + 32768;
    unsigned short* BdB1 = smem + 49152;

    floatx4 acc[8][4];
#pragma unroll
    for (int i = 0; i < 8; ++i)
#pragma unroll
        for (int j = 0; j < 4; ++j) acc[i][j] = (floatx4){0.f, 0.f, 0.f, 0.f};

    auto STAGE = [&](unsigned short* Ad, unsigned short* Bd, int tt, int p) {
        long k0 = (long)tt * GBK;
        if (k0 + GBK > Kloop) k0 = 0;    // dummy prefetch past K keeps vmcnt exact
        const int seg = p * 8 + wid;     // 8-row segment; wave writes seg*1024B linearly
        const long ro = (long)(seg * 8 + s_r) * ldk + k0 + s_kg * 8;
        gload_lds16(Ag + ro, Ad + seg * 512);
        gload_lds16(Bg + ro, Bd + seg * 512);
    };

    // prologue: tile0 pairs 0-3 + tile1 pairs 0-1; drain tile0, keep 4 in flight
#pragma unroll
    for (int p = 0; p < 4; ++p) STAGE(AdB0, BdB0, 0, p);
    STAGE(AdB1, BdB1, 1, 0);
    STAGE(AdB1, BdB1, 1, 1);
    VMC4;
    BAR;
    SB0;

    const int nk = Kloop / GBK;          // even for all call sites

    auto tile_step = [&](const AS3 unsigned short* pAk0, const AS3 unsigned short* pAk1,
                         const AS3 unsigned short* pBk0, const AS3 unsigned short* pBk1,
                         unsigned short* AdC, unsigned short* BdC,
                         unsigned short* AdN, unsigned short* BdN, int t) {
        intx4 aL[4][2], aH[4][2], bV[4][2];
        // ---- phase 0: read aLo(m0-3) + b(n0-1); stage (t+1,pair2) ----
        DSR(aL[0][0], pAk0, "0");     DSR(aL[0][1], pAk1, "0");
        DSR(aL[1][0], pAk0, "2048");  DSR(aL[1][1], pAk1, "2048");
        DSR(aL[2][0], pAk0, "4096");  DSR(aL[2][1], pAk1, "4096");
        DSR(aL[3][0], pAk0, "6144");  DSR(aL[3][1], pAk1, "6144");
        DSR(bV[0][0], pBk0, "0");     DSR(bV[0][1], pBk1, "0");
        DSR(bV[1][0], pBk0, "2048");  DSR(bV[1][1], pBk1, "2048");
        STAGE(AdN, BdN, t + 1, 2);
        SB0; BAR; LGKM0; SB0;
        __builtin_amdgcn_s_setprio(1);
#pragma unroll
        for (int m = 0; m < 4; ++m)
#pragma unroll
            for (int n = 0; n < 2; ++n)
#pragma unroll
                for (int ks = 0; ks < 2; ++ks)
                    acc[m][n] = __builtin_amdgcn_mfma_f32_16x16x32_bf16(asv(aL[m][ks]), asv(bV[n][ks]), acc[m][n], 0, 0, 0);
        __builtin_amdgcn_s_setprio(0);
        SB0; BAR;
        // ---- phase 1: read b(n2-3); stage (t+1,pair3) ----
        DSR(bV[2][0], pBk0, "4096");  DSR(bV[2][1], pBk1, "4096");
        DSR(bV[3][0], pBk0, "6144");  DSR(bV[3][1], pBk1, "6144");
        STAGE(AdN, BdN, t + 1, 3);
        SB0; BAR; LGKM0; SB0;
        __builtin_amdgcn_s_setprio(1);
#pragma unroll
        for (int m = 0; m < 4; ++m)
#pragma unroll
            for (int n = 2; n < 4; ++n)
#pragma unroll
                for (int ks = 0; ks < 2; ++ks)
                    acc[m][n] = __builtin_amdgcn_mfma_f32_16x16x32_bf16(asv(aL[m][ks]), asv(bV[n][ks]), acc[m][n], 0, 0, 0);
        __builtin_amdgcn_s_setprio(0);
        SB0; BAR;
        // ---- phase 2: read aHi(m4-7); stage (t+2,pair0) -> CURRENT buf ----
        DSR(aH[0][0], pAk0, "8192");  DSR(aH[0][1], pAk1, "8192");
        DSR(aH[1][0], pAk0, "10240"); DSR(aH[1][1], pAk1, "10240");
        DSR(aH[2][0], pAk0, "12288"); DSR(aH[2][1], pAk1, "12288");
        DSR(aH[3][0], pAk0, "14336"); DSR(aH[3][1], pAk1, "14336");
        STAGE(AdC, BdC, t + 2, 0);
        SB0; BAR; LGKM0; SB0;
        __builtin_amdgcn_s_setprio(1);
#pragma unroll
        for (int m = 0; m < 4; ++m)
#pragma unroll
            for (int n = 2; n < 4; ++n)
#pragma unroll
                for (int ks = 0; ks < 2; ++ks)
                    acc[m + 4][n] = __builtin_amdgcn_mfma_f32_16x16x32_bf16(asv(aH[m][ks]), asv(bV[n][ks]), acc[m + 4][n], 0, 0, 0);
        __builtin_amdgcn_s_setprio(0);
        SB0; BAR;
        // ---- phase 3: stage (t+2,pair1); counted drain ----
        STAGE(AdC, BdC, t + 2, 1);
        SB0; BAR; SB0;
        __builtin_amdgcn_s_setprio(1);
#pragma unroll
        for (int m = 0; m < 4; ++m)
#pragma unroll
            for (int n = 0; n < 2; ++n)
#pragma unroll
                for (int ks = 0; ks < 2; ++ks)
                    acc[m + 4][n] = __builtin_amdgcn_mfma_f32_16x16x32_bf16(asv(aH[m][ks]), asv(bV[n][ks]), acc[m + 4][n], 0, 0, 0);
        __builtin_amdgcn_s_setprio(0);
        // drain tile t+1's 8 loads; keep tile t+2's pair0/pair1 (4) in flight
        VMC4; SB0; BAR;
    };

#pragma unroll 1
    for (int t = 0; t < nk; t += 2) {
        tile_step(pA0k0, pA0k1, pB0k0, pB0k1, AdB0, BdB0, AdB1, BdB1, t);
        tile_step(pA1k0, pA1k1, pB1k0, pB1k1, AdB1, BdB1, AdB0, BdB0, t + 1);
    }

    // ---- epilogue: C/D layout col=lane&15, row=(lane>>4)*4+reg ----
    const int rcol = lane & 15, rrow = (lane >> 4) * 4;
#pragma unroll
    for (int m = 0; m < 8; ++m)
#pragma unroll
        for (int n = 0; n < 4; ++n) {
            const int colb = bn * GBN + wn + n * 16;
            if (colb >= Nvalid) continue;   // pad-tile fragments (garbage B) masked
            const int col = colb + rcol;
#pragma unroll
            for (int r2 = 0; r2 < 4; ++r2) {
                const int row = bm * GBM + wm + m * 16 + rrow + r2;
                float v = acc[m][n][r2];
                if (BF16OUT) {
                    ((unsigned short*)Cout)[(long)row * ldc + col] = f2bf(v);
                    if (aux && col >= auxc0 && col < auxc0 + 64)
                        aux[(long)row * 64 + (col - auxc0)] = v;
                } else {
                    float* op = bz ? Cpart : (float*)Cout;
                    op[(long)row * ldc + col] = v;
                }
            }
        }
}

// ---------------- split-K reduction: dst += src (f32, vectorized) ----------------
__global__ void k_add(float* __restrict__ dst, const float* __restrict__ src, long n4) {
    long i = (long)blockIdx.x * blockDim.x + threadIdx.x;
    if (i >= n4) return;
    float4 a = ((const float4*)src)[i];
    float4 d = ((float4*)dst)[i];
    d.x += a.x; d.y += a.y; d.z += a.z; d.w += a.w;
    ((float4*)dst)[i] = d;
}

// ---------------- causal conv1d (k=4) + SiLU, bf16 in/out ----------------
__global__ void k_conv(const unsigned short* __restrict__ xbcd, const float* __restrict__ convw,
                       unsigned short* __restrict__ xc) {
    long i = (long)blockIdx.x * 256 + threadIdx.x;
    if (i >= (long)SEQ * CONV_DIM) return;
    int c = (int)(i % CONV_DIM);
    int s = (int)(i / CONV_DIM);
    float w0 = convw[c * 4 + 0], w1 = convw[c * 4 + 1];
    float w2 = convw[c * 4 + 2], w3 = convw[c * 4 + 3];
    float acc = bf2f(xbcd[(long)s * XBCD_N + c]) * w3;
    if (s >= 1) acc += bf2f(xbcd[(long)(s - 1) * XBCD_N + c]) * w2;
    if (s >= 2) acc += bf2f(xbcd[(long)(s - 2) * XBCD_N + c]) * w1;
    if (s >= 3) acc += bf2f(xbcd[(long)(s - 3) * XBCD_N + c]) * w0;
    float sl = acc / (1.f + __expf(-acc));
    xc[i] = f2bf(sl);
}

// ---------------- dt = softplus(dtraw+bias), dA = dt*A, per-chunk inclusive cumsum ----------------
__global__ __launch_bounds__(256) void k_dt(const float* __restrict__ dtraw,
        const float* __restrict__ dt_bias, const float* __restrict__ A_log,
        float* __restrict__ dtv, float* __restrict__ dAc, float* __restrict__ dAlast)
{
    int c = blockIdx.x, h = blockIdx.y;
    int l = threadIdx.x;
    __shared__ float sh[CHUNK];
    float v = dtraw[(long)(c * CHUNK + l) * 64 + h] + dt_bias[h];
    float dt = (v > 20.f) ? v : log1pf(__expf(v));
    float Ah = -__expf(A_log[h]);
    float dA = dt * Ah;
    sh[l] = dA;
    __syncthreads();
    float x = dA;
#pragma unroll
    for (int off = 1; off < CHUNK; off <<= 1) {
        float t = (l >= off) ? sh[l - off] : 0.f;
        __syncthreads();
        x += t;
        sh[l] = x;
        __syncthreads();
    }
    dtv[(long)(c * CHUNK + l) * HEADS + h] = dt;
    dAc[(long)(c * CHUNK + l) * HEADS + h] = x;
    if (l == CHUNK - 1) dAlast[c * HEADS + h] = x;
}

// ---------------- G[c][l][s] = C[l] . B[s] ----------------
__global__ __launch_bounds__(256) void k_G(const unsigned short* __restrict__ xc, float* __restrict__ G) {
    int c = blockIdx.x, l = blockIdx.y;
    int s = threadIdx.x;
    __shared__ float Csh[STATE];
    if (s < STATE) Csh[s] = bf2f(xc[(long)(c * CHUNK + l) * CONV_DIM + HID + STATE + s]);
    __syncthreads();
    const unsigned short* Brow = xc + (long)(c * CHUNK + s) * CONV_DIM + HID;
    float acc = 0.f;
#pragma unroll
    for (int n = 0; n < STATE; n += 8) {
        short8 b8 = *(const short8*)&Brow[n];
#pragma unroll
        for (int j = 0; j < 8; ++j)
            acc += Csh[n + j] * bf2f((unsigned short)b8[j]);
    }
    G[((long)c * CHUNK + l) * CHUNK + s] = acc;
}

// ---------------- states[c,h,p,n] = sum_l B[l,n]*exp(dAlast-dAc[l])*dt[l]*xh[l,p] ----------------
__global__ __launch_bounds__(256) void k_states(
    const unsigned short* __restrict__ xc, const float* __restrict__ dtv,
    const float* __restrict__ dAc, const float* __restrict__ dAlast,
    float* __restrict__ states)
{
    int c = blockIdx.x, h = blockIdx.y;
    int t = threadIdx.x;
    __shared__ float xs[64][64];
    __shared__ float dA_sh[CHUNK], dt_sh[CHUNK];
    long base_s = (long)c * CHUNK;
    dA_sh[t] = dAc[(base_s + t) * HEADS + h];
    dt_sh[t] = dtv[(base_s + t) * HEADS + h];
    __syncthreads();
    float dAl = dAlast[c * HEADS + h];
    int p0 = t >> 5;
    int n0 = t & 31;
    float acc[8][4];
#pragma unroll
    for (int ip = 0; ip < 8; ++ip)
#pragma unroll
        for (int j = 0; j < 4; ++j) acc[ip][j] = 0.f;

    for (int lb = 0; lb < 4; ++lb) {
#pragma unroll
        for (int i = 0; i < 16; ++i) {
            int e = t + i * 256;
            int r = e >> 6, pcol = e & 63;
            float ds = __expf(dAl - dA_sh[lb * 64 + r]) * dt_sh[lb * 64 + r];
            xs[r][pcol] = bf2f(xc[(base_s + lb * 64 + r) * CONV_DIM + h * HEAD_DIM + pcol]) * ds;
        }
        __syncthreads();
        for (int lp = 0; lp < 64; ++lp) {
            const unsigned short* Brow = xc + (base_s + lb * 64 + lp) * CONV_DIM + HID;
            float bv[4];
#pragma unroll
            for (int j = 0; j < 4; ++j) bv[j] = bf2f(Brow[n0 + 32 * j]);
#pragma unroll
            for (int ip = 0; ip < 8; ++ip) {
                float xv = xs[lp][p0 + 8 * ip];
#pragma unroll
                for (int j = 0; j < 4; ++j) acc[ip][j] += xv * bv[j];
            }
        }
        __syncthreads();
    }
    float* Sb = states + (long)(c * HEADS + h) * HEAD_DIM * STATE;
#pragma unroll
    for (int ip = 0; ip < 8; ++ip)
#pragma unroll
        for (int j = 0; j < 4; ++j)
            Sb[(p0 + 8 * ip) * STATE + n0 + 32 * j] = acc[ip][j];
}

// ---------------- sequential chunk-state scan (in place: states[c] := prev state) ----------------
__global__ void k_scan(float* __restrict__ states, const float* __restrict__ dAlast) {
    int t = blockIdx.x * 256 + threadIdx.x;
    if (t >= HEADS * HEAD_DIM * STATE) return;
    int h = t >> 13;
    const long stride = (long)HEADS * HEAD_DIM * STATE;
    float carry = 0.f;
    for (int c = 0; c < NCHUNK; ++c) {
        float s = states[c * stride + t];
        float dec = __expf(dAlast[c * HEADS + h]);
        states[c * stride + t] = carry;
        carry = carry * dec + s;
    }
}

// ---------------- y = y_off + y_diag + D*x (MFMA version), bf16 out ----------------
#define XDTS 264   // row stride: 528 B -> 16B-aligned rows, 4-bank advance (2-way, free)
#define PVS  136   // row stride: 272 B -> same property
__global__ __launch_bounds__(256, 3) void k_ssd_y(
    const unsigned short* __restrict__ xc, const float* __restrict__ G,
    const float* __restrict__ dtv, const float* __restrict__ dAc,
    const float* __restrict__ prev, const float* __restrict__ Dp,
    unsigned short* __restrict__ y)
{
    __shared__ __attribute__((aligned(16))) unsigned short xdtT[64 * XDTS];
    __shared__ __attribute__((aligned(16))) unsigned short pvB[64 * PVS];
    __shared__ float dA_sh[CHUNK];
    __shared__ float dt_sh[CHUNK];
    const int c = blockIdx.x, h = blockIdx.y;
    const int t = threadIdx.x;
    const int w = t >> 6, lane = t & 63;
    const long base_s = (long)c * CHUNK;

    dA_sh[t] = dAc[(base_s + t) * HEADS + h];
    dt_sh[t] = dtv[(base_s + t) * HEADS + h];
    __syncthreads();

    {
        const float* Pb = prev + (long)(c * HEADS + h) * HEAD_DIM * STATE;
#pragma unroll
        for (int i = 0; i < 32; ++i) {
            int e = t + i * 256;
            int p = e >> 7, n = e & 127;
            pvB[p * PVS + n] = f2bf(Pb[e]);
        }
    }
#pragma unroll
    for (int i = 0; i < 64; ++i) {
        int e = t + i * 256;
        int p = e & 63, s = e >> 6;
        float v = bf2f(xc[(base_s + s) * CONV_DIM + h * HEAD_DIM + p]) * dt_sh[s];
        xdtT[p * XDTS + s] = f2bf(v);
    }
    __syncthreads();

    floatx4 acc[4][4];
#pragma unroll
    for (int i = 0; i < 4; ++i)
#pragma unroll
        for (int j = 0; j < 4; ++j) acc[i][j] = (floatx4){0.f, 0.f, 0.f, 0.f};

    const int lrow = lane & 15;
    const int kgrp = (lane >> 4) * 8;
    float myA[4], eAl[4];
#pragma unroll
    for (int i = 0; i < 4; ++i) {
        int l = w * 64 + i * 16 + lrow;
        myA[i] = dA_sh[l];
        eAl[i] = __expf(myA[i]);
    }

    // ---- off term: k = n over STATE ----
    for (int k0 = 0; k0 < STATE; k0 += 32) {
        short8 af[4], bfr[4];
#pragma unroll
        for (int i = 0; i < 4; ++i) {
            int l = w * 64 + i * 16 + lrow;
            union { short8 v; unsigned short u[8]; } r, o;
            r.v = *(const short8*)&xc[(base_s + l) * CONV_DIM + (HID + STATE) + k0 + kgrp];
#pragma unroll
            for (int j = 0; j < 8; ++j) o.u[j] = f2bf(bf2f(r.u[j]) * eAl[i]);
            af[i] = o.v;
        }
#pragma unroll
        for (int j = 0; j < 4; ++j)
            bfr[j] = *(const short8*)&pvB[(j * 16 + lrow) * PVS + k0 + kgrp];
#pragma unroll
        for (int i = 0; i < 4; ++i)
#pragma unroll
            for (int j = 0; j < 4; ++j)
                acc[i][j] = __builtin_amdgcn_mfma_f32_16x16x32_bf16(af[i], bfr[j], acc[i][j], 0, 0, 0);
    }

    // ---- diag term: k = s, only tiles not fully above the diagonal ----
    for (int k0 = 0; k0 < (w + 1) * 64; k0 += 32) {
        short8 af[4], bfr[4];
#pragma unroll
        for (int i = 0; i < 4; ++i) {
            int l = w * 64 + i * 16 + lrow;
            const float* Gp = G + (base_s + l) * (long)CHUNK + k0 + kgrp;
            float4 g0 = *(const float4*)Gp;
            float4 g1 = *(const float4*)(Gp + 4);
            float ga[8] = {g0.x, g0.y, g0.z, g0.w, g1.x, g1.y, g1.z, g1.w};
            union { short8 v; unsigned short u[8]; } o;
#pragma unroll
            for (int j = 0; j < 8; ++j) {
                int s = k0 + kgrp + j;
                float e = __expf(fminf(myA[i] - dA_sh[s], 0.f));
                float m = (s <= l) ? ga[j] * e : 0.f;
                o.u[j] = f2bf(m);
            }
            af[i] = o.v;
        }
#pragma unroll
        for (int j = 0; j < 4; ++j)
            bfr[j] = *(const short8*)&xdtT[(j * 16 + lrow) * XDTS + k0 + kgrp];
#pragma unroll
        for (int i = 0; i < 4; ++i)
#pragma unroll
            for (int j = 0; j < 4; ++j)
                acc[i][j] = __builtin_amdgcn_mfma_f32_16x16x32_bf16(af[i], bfr[j], acc[i][j], 0, 0, 0);
    }

    // ---- epilogue: + D*x, bf16 store ----
    const float Dh = Dp[h];
    const int rrow = (lane >> 4) * 4;
#pragma unroll
    for (int i = 0; i < 4; ++i)
#pragma unroll
        for (int j = 0; j < 4; ++j) {
            int p = j * 16 + lrow;
#pragma unroll
            for (int r = 0; r < 4; ++r) {
                int l = w * 64 + i * 16 + rrow + r;
                float v = acc[i][j][r] + Dh * bf2f(xc[(base_s + l) * CONV_DIM + h * HEAD_DIM + p]);
                y[(base_s + l) * (long)HID + h * HEAD_DIM + p] = f2bf(v);
            }
        }
}

// ---------------- gate with silu(z), RMSNorm, bf16 out ----------------
__global__ __launch_bounds__(256) void k_norm(
    const unsigned short* __restrict__ y, const unsigned short* __restrict__ z,
    const float* __restrict__ norm_w, unsigned short* __restrict__ yb)
{
    int s = blockIdx.x;
    int t = threadIdx.x;
    const unsigned short* yrow = y + (long)s * HID;
    const unsigned short* zrow = z + (long)s * HID;
    float vals[16];
    float ss = 0.f;
#pragma unroll
    for (int i = 0; i < 16; ++i) {
        int j = t + i * 256;
        float yv = bf2f(yrow[j]);
        float zv = bf2f(zrow[j]);
        float g = yv * (zv / (1.f + __expf(-zv)));
        vals[i] = g;
        ss += g * g;
    }
#pragma unroll
    for (int off = 32; off > 0; off >>= 1) ss += __shfl_down(ss, off);
    __shared__ float wsum[4];
    int lane = t & 63, wid = t >> 6;
    if (lane == 0) wsum[wid] = ss;
    __syncthreads();
    float total = wsum[0] + wsum[1] + wsum[2] + wsum[3];
    float scale = rsqrtf(total / HID + 1e-5f);
#pragma unroll
    for (int i = 0; i < 16; ++i) {
        int j = t + i * 256;
        yb[(long)s * HID + j] = f2bf(vals[i] * scale * norm_w[j]);
    }
}

// ---------------- launch ----------------
extern "C" void kernel_launch(void* const* d_in, const int* in_sizes, int n_in,
                              void* d_out, int out_size, void* d_ws, size_t ws_size,
                              hipStream_t stream) {
    const float* x          = (const float*)d_in[0];
    const float* in_proj_w  = (const float*)d_in[1];
    const float* conv_w     = (const float*)d_in[2];
    const float* dt_bias    = (const float*)d_in[3];
    const float* A_log      = (const float*)d_in[4];
    const float* Dp         = (const float*)d_in[5];
    const float* norm_w     = (const float*)d_in[6];
    const float* out_proj_w = (const float*)d_in[7];
    char* ws = (char*)d_ws;

    // workspace layout (bytes) — total 131,600,384 (unchanged)
    const size_t off_xb    = 0;
    const size_t off_wbin  = off_xb    + (size_t)SEQ * DIMIN * 2;
    const size_t off_xbcd  = off_wbin  + (size_t)WROWS * DIMIN * 2;
    const size_t off_xc    = off_xbcd  + (size_t)SEQ * XBCD_N * 2;
    const size_t off_dtraw = off_xc    + (size_t)SEQ * CONV_DIM * 2;
    const size_t off_dtv   = off_dtraw + (size_t)SEQ * 64 * 4;
    const size_t off_dAc   = off_dtv   + (size_t)SEQ * HEADS * 4;
    const size_t off_dAl   = off_dAc   + (size_t)SEQ * HEADS * 4;
    const size_t off_G     = off_dAl   + (size_t)NCHUNK * HEADS * 4;
    const size_t needed    = off_G     + (size_t)NCHUNK * CHUNK * CHUNK * 4;
    if (ws_size < needed) return;

    unsigned short* xb    = (unsigned short*)(ws + off_xb);
    unsigned short* wbin  = (unsigned short*)(ws + off_wbin);
    unsigned short* xbcd  = (unsigned short*)(ws + off_xbcd);
    unsigned short* xc    = (unsigned short*)(ws + off_xc);
    float* dtraw = (float*)(ws + off_dtraw);
    float* dtv   = (float*)(ws + off_dtv);
    float* dAc   = (float*)(ws + off_dAc);
    float* dAl   = (float*)(ws + off_dAl);
    float* G     = (float*)(ws + off_G);

    float* states      = (float*)d_out;
    unsigned short* z  = (unsigned short*)d_out;
    unsigned short* y  = xbcd;
    unsigned short* yb = xc;
    unsigned short* wob = wbin;
    float* gpart = (float*)(ws + off_xbcd);   // split-K partials; xbcd dead by GEMM3

    { long n = (long)SEQ * DIMIN;
      k_convert<<<(unsigned)((n + 255) / 256), 256, 0, stream>>>(x, xb, n, n); }
    { long n = (long)WROWS * DIMIN, nsrc = (long)D_IN * DIMIN;
      k_convert<<<(unsigned)((n + 255) / 256), 256, 0, stream>>>(in_proj_w, wbin, n, nsrc); }
    // GEMM1: xBC+dt. 18 N-tiles (4608 covered, stores masked to <4480);
    // B rows 4480-4607 over-read land in allocated ws and feed masked fragments only.
    k_gemm256<1><<<dim3((XBCD_N + GBN - 1) / GBN, SEQ / GBM, 1), 512, 0, stream>>>(
        xb, wbin + (size_t)HID * DIMIN, (void*)xbcd, nullptr,
        DIMIN, DIMIN, XBCD_N, XBCD_N, dtraw, 4352);
    { long n = (long)SEQ * CONV_DIM;
      k_conv<<<(unsigned)((n + 255) / 256), 256, 0, stream>>>(xbcd, conv_w, xc); }
    k_dt<<<dim3(NCHUNK, HEADS), 256, 0, stream>>>(dtraw, dt_bias, A_log, dtv, dAc, dAl);
    k_G<<<dim3(NCHUNK, CHUNK), 256, 0, stream>>>(xc, G);
    k_states<<<dim3(NCHUNK, HEADS), 256, 0, stream>>>(xc, dtv, dAc, dAl, states);
    k_scan<<<(HEADS * HEAD_DIM * STATE) / 256, 256, 0, stream>>>(states, dAl);
    k_ssd_y<<<dim3(NCHUNK, HEADS), 256, 0, stream>>>(xc, G, dtv, dAc, states, Dp, y);
    // GEMM2: z-gate (16x16 tiles = 256 blocks, exactly 1/CU)
    k_gemm256<1><<<dim3(HID / GBN, SEQ / GBM, 1), 512, 0, stream>>>(
        xb, wbin, (void*)z, nullptr, DIMIN, DIMIN, HID, HID, nullptr, 0);
    k_norm<<<SEQ, 256, 0, stream>>>(y, z, norm_w, yb);
    { long n = (long)DIMIN * HID;
      k_convert<<<(unsigned)((n + 255) / 256), 256, 0, stream>>>(out_proj_w, wob, n, n); }
    // GEMM3: out-proj, split-K=2 (8x16x2 = 256 blocks); z=1 partials -> gpart
    k_gemm256<0><<<dim3(DIMIN / GBN, SEQ / GBM, 2), 512, 0, stream>>>(
        yb, wob, d_out, gpart, HID / 2, HID, DIMIN, DIMIN, nullptr, 0);
    k_add<<<(unsigned)(((long)SEQ * DIMIN / 4 + 255) / 256), 256, 0, stream>>>(
        (float*)d_out, gpart, (long)SEQ * DIMIN / 4);
}